// Round 3
// baseline (47.609 us; speedup 1.0000x reference)
//
#include <hip/hip_runtime.h>
#include <stdint.h>

#define DT (1.0f / 120.0f)

struct M2 { float a00, a01, a10, a11; };

__device__ __forceinline__ M2 mmul(const M2& x, const M2& y) {
    // row-vector convention: v@(X*Y) = (v@X)@Y
    M2 r;
    r.a00 = x.a00 * y.a00 + x.a01 * y.a10;
    r.a01 = x.a00 * y.a01 + x.a01 * y.a11;
    r.a10 = x.a10 * y.a00 + x.a11 * y.a10;
    r.a11 = x.a10 * y.a01 + x.a11 * y.a11;
    return r;
}

__device__ __forceinline__ float2 vmul(float2 v, const M2& m) {
    return make_float2(v.x * m.a00 + v.y * m.a10,
                       v.x * m.a01 + v.y * m.a11);
}

// Async global->LDS, 16B per lane. LDS dest = wave-uniform base + lane*16.
#define GLOAD_LDS16(gp, lp) __builtin_amdgcn_global_load_lds(                 \
    (const __attribute__((address_space(1))) void*)(gp),                      \
    (__attribute__((address_space(3))) void*)(lp), 16, 0, 0)

// One block per batch row. Linear-recurrence parallel scan:
//   X_t = X_{t-1} @ A + u_t @ W
// All global traffic coalesced via a per-wave LDS bounce with slot swizzle
//   f(q) = q ^ ((q>>3)&7)   (involution on 16-B slots within a wave's region)
// Per-wave staging (own vmcnt wait, wave-ordered LDS) -> only 2 block
// barriers (around the 4-entry wave-total scan). Wave totals live in the
// first slot of each wave's own buf region => LDS is exactly 32 KiB
// => 5 blocks/CU instead of 4.
template <int C, int BLOCK>
__global__ __launch_bounds__(BLOCK) void spring_scan(
    const float* __restrict__ u, const float* __restrict__ x0,
    const float* __restrict__ k_w, const float* __restrict__ b_w,
    const float* __restrict__ im, const float* __restrict__ imask,
    float* __restrict__ out, int T)
{
    static_assert(C == 16, "squaring count + swizzle assume C==16");
    constexpr int NW     = BLOCK / 64;
    constexpr int SLOTS  = BLOCK * C / 2;   // float4 slots per tile (2048 = 32KB)
    constexpr int WSLOTS = 64 * C / 2;      // slots per wave region (512)

    __shared__ float4 buf[SLOTS];           // exactly 32768 B

    const int brow = blockIdx.x;
    const int tid  = threadIdx.x;
    const int lane = tid & 63;
    const int wid  = tid >> 6;
    const int wbase = wid * WSLOTS;

    const long rowbase = (long)brow * T * 2;
    const float4* urow4 = (const float4*)(u + rowbase);
    float4*       orow4 = (float4*)(out + rowbase);

    constexpr int STEPS = C * BLOCK;

    // ---- issue tile-0 staging immediately (hide latency under preamble) ----
    // LDS[wbase + j*64 + l] = G[tile + wbase + j*64 + (l ^ (l>>3))]
    {
        const int lsw = lane ^ (lane >> 3);
        #pragma unroll
        for (int j = 0; j < C / 2; ++j)
            GLOAD_LDS16(urow4 + wbase + j * 64 + lsw, &buf[wbase + j * 64]);
    }

    // ---- scalar preamble (overlaps with in-flight loads) ----
    const float k  = fabsf(k_w[0]);
    const float bd = fabsf(b_w[0]);
    const float W00 = im[0] * imask[0] * DT, W01 = im[1] * imask[1] * DT;
    const float W10 = im[2] * imask[2] * DT, W11 = im[3] * imask[3] * DT;

    // x_new = x + v*DT ; v_new = -k*DT*x + (1-b*DT)*v   (row-vec right-mul)
    M2 A = { 1.0f, -k * DT, DT, 1.0f - bd * DT };

    // P[s] = A^(C * 2^s);  P[0] = A^16 via 4 squarings; P[6] = A^1024
    M2 P[7];
    {
        M2 t = A;
        #pragma unroll
        for (int i = 0; i < 4; ++i) t = mmul(t, t);
        P[0] = t;
        #pragma unroll
        for (int s = 1; s < 7; ++s) P[s] = mmul(P[s - 1], P[s - 1]);
    }
    // Mlane = A^(C*lane) from bits of lane (powers of A commute)
    M2 Mlane = { 1.f, 0.f, 0.f, 1.f };
    #pragma unroll
    for (int s = 0; s < 6; ++s)
        if ((lane >> s) & 1) Mlane = mmul(Mlane, P[s]);

    float2 X_init = make_float2(x0[brow * 2 + 0], x0[brow * 2 + 1]);

    for (int t0 = 0; t0 < T; t0 += STEPS) {
        const int tilebase = t0 / 2;  // float4 slot index of tile start

        // ---- per-wave wait for this wave's staging ----
        asm volatile("s_waitcnt vmcnt(0)" ::: "memory");
        __builtin_amdgcn_sched_barrier(0);

        // ---- read own 128B chunk (swizzled ds_read_b128) + W transform ----
        float2 c[C];
        #pragma unroll
        for (int m = 0; m < C / 2; ++m) {
            float4 t = buf[wbase + lane * (C / 2) + (m ^ (lane & 7))];
            c[2 * m + 0] = make_float2(t.x * W00 + t.y * W10,
                                       t.x * W01 + t.y * W11);
            c[2 * m + 1] = make_float2(t.z * W00 + t.w * W10,
                                       t.z * W01 + t.w * W11);
        }

        // ---- local zero-seeded contribution over C steps ----
        float2 v = make_float2(0.f, 0.f);
        #pragma unroll
        for (int i = 0; i < C; ++i) {
            v = vmul(v, A);
            v.x += c[i].x; v.y += c[i].y;
        }

        // ---- wave-level inclusive scan (64 lanes, 6 steps) ----
        #pragma unroll
        for (int s = 0; s < 6; ++s) {
            float px = __shfl_up(v.x, 1u << s, 64);
            float py = __shfl_up(v.y, 1u << s, 64);
            if (lane >= (1 << s)) {
                float2 pv = vmul(make_float2(px, py), P[s]);
                v.x = pv.x + v.x; v.y = pv.y + v.y;
            }
        }

        // ---- wave total -> first slot of OWN region (same-wave ordered:
        //      this wave already consumed its input slots) ----
        if (lane == 63) *(float2*)&buf[wbase] = v;
        __syncthreads();                             // barrier 1: tots visible

        // off = actual state at the start of this wave's 1024-step span
        float2 off = X_init;
        for (int w2 = 0; w2 < wid; ++w2) {
            off = vmul(off, P[6]);
            float2 tw = *(const float2*)&buf[w2 * WSLOTS];
            off.x += tw.x; off.y += tw.y;
        }

        // carry to next tile (register-stashed before tots get clobbered)
        const bool carry = (t0 + STEPS < T);
        float2 fin;
        if (carry) {
            fin = X_init;
            #pragma unroll
            for (int w2 = 0; w2 < NW; ++w2) {
                fin = vmul(fin, P[6]);
                float2 tw = *(const float2*)&buf[w2 * WSLOTS];
                fin.x += tw.x; fin.y += tw.y;
            }
        }

        // exclusive within-wave prefix
        float ex = __shfl_up(v.x, 1u, 64);
        float ey = __shfl_up(v.y, 1u, 64);
        float2 vex = (lane == 0) ? make_float2(0.f, 0.f) : make_float2(ex, ey);

        // start state for this thread's chunk
        float2 X = vmul(off, Mlane);
        X.x += vex.x; X.y += vex.y;

        __syncthreads();                             // barrier 2: tots all read

        // ---- replay C steps in order; write pairs to own swizzled slots ----
        #pragma unroll
        for (int m = 0; m < C / 2; ++m) {
            float4 o;
            X = vmul(X, A);
            X.x += c[2 * m + 0].x; X.y += c[2 * m + 0].y;
            o.x = X.x; o.y = X.y;
            X = vmul(X, A);
            X.x += c[2 * m + 1].x; X.y += c[2 * m + 1].y;
            o.z = X.x; o.w = X.y;
            buf[wbase + lane * (C / 2) + (m ^ (lane & 7))] = o;
        }

        // ---- coalesced store from OWN wave region (wave-ordered LDS) ----
        {
            const int lsw = lane ^ (lane >> 3);
            #pragma unroll
            for (int j = 0; j < C / 2; ++j)
                orow4[tilebase + wbase + j * 64 + lsw] = buf[wbase + j * 64 + lane];
        }

        // ---- next tile: barrier (drain ds reads) then restage own region ----
        if (carry) {
            X_init = fin;
            __syncthreads();
            const int lsw = lane ^ (lane >> 3);
            const int nb  = tilebase + SLOTS;
            #pragma unroll
            for (int j = 0; j < C / 2; ++j)
                GLOAD_LDS16(urow4 + nb + wbase + j * 64 + lsw, &buf[wbase + j * 64]);
        }
    }
}

extern "C" void kernel_launch(void* const* d_in, const int* in_sizes, int n_in,
                              void* d_out, int out_size, void* d_ws, size_t ws_size,
                              hipStream_t stream) {
    const float* u     = (const float*)d_in[0];
    const float* x0    = (const float*)d_in[1];
    const float* k_w   = (const float*)d_in[2];
    const float* b_w   = (const float*)d_in[3];
    const float* im    = (const float*)d_in[4];
    const float* imask = (const float*)d_in[5];
    float* out = (float*)d_out;

    const int B = in_sizes[1] / 2;        // x0 is (B,2)
    const int T = in_sizes[0] / (2 * B);  // u is (B,T,2)

    spring_scan<16, 256><<<B, 256, 0, stream>>>(u, x0, k_w, b_w, im, imask, out, T);
}

// Round 4
// 46.954 us; speedup vs baseline: 1.0140x; 1.0140x over previous
//
#include <hip/hip_runtime.h>
#include <stdint.h>

#define DT (1.0f / 120.0f)

struct M2 { float a00, a01, a10, a11; };

__device__ __forceinline__ M2 mmul(const M2& x, const M2& y) {
    // row-vector convention: v@(X*Y) = (v@X)@Y
    M2 r;
    r.a00 = x.a00 * y.a00 + x.a01 * y.a10;
    r.a01 = x.a00 * y.a01 + x.a01 * y.a11;
    r.a10 = x.a10 * y.a00 + x.a11 * y.a10;
    r.a11 = x.a10 * y.a01 + x.a11 * y.a11;
    return r;
}

__device__ __forceinline__ float2 vmul(float2 v, const M2& m) {
    return make_float2(v.x * m.a00 + v.y * m.a10,
                       v.x * m.a01 + v.y * m.a11);
}

// wave-uniform float -> SGPR (frees VGPRs; VALU reads SGPR operand directly)
__device__ __forceinline__ float rfl(float x) {
    return __uint_as_float((unsigned)__builtin_amdgcn_readfirstlane((int)__float_as_uint(x)));
}
__device__ __forceinline__ M2 rflm(M2 m) {
    return { rfl(m.a00), rfl(m.a01), rfl(m.a10), rfl(m.a11) };
}

// Async global->LDS, 16B per lane. LDS dest = wave-uniform base + lane*16.
#define GLOAD_LDS16(gp, lp) __builtin_amdgcn_global_load_lds(                 \
    (const __attribute__((address_space(1))) void*)(gp),                      \
    (__attribute__((address_space(3))) void*)(lp), 16, 0, 0)

// One block per batch row; linear-recurrence parallel scan
//   X_t = X_{t-1} @ A + u_t @ W
// C=8 steps/thread, 2 tiles of 2048 steps. 16 KiB LDS bounce per block with
// slot swizzle (involution on 16B slots within a wave region):
//   g(p) = p ^ ((p>>3)&3)     [staging source / store dest]
//   chunk read quarter q = m ^ ((lane>>1)&3)
// Wave-uniform matrices live in SGPRs (readfirstlane) so VGPR<=64 and
// __launch_bounds__(256,8) gives 8 blocks/CU = 32 waves (max occupancy).
template <int C, int BLOCK>
__global__ __launch_bounds__(BLOCK, 8) void spring_scan(
    const float* __restrict__ u, const float* __restrict__ x0,
    const float* __restrict__ k_w, const float* __restrict__ b_w,
    const float* __restrict__ im, const float* __restrict__ imask,
    float* __restrict__ out, int T)
{
    static_assert(C == 8, "squaring count + swizzle assume C==8");
    constexpr int NW     = BLOCK / 64;     // 4 waves
    constexpr int SLOTS  = BLOCK * C / 2;  // 1024 float4 slots = 16 KiB
    constexpr int WSLOTS = 64 * C / 2;     // 256 slots per wave region

    __shared__ float4 buf[SLOTS];          // exactly 16384 B

    const int brow  = blockIdx.x;
    const int tid   = threadIdx.x;
    const int lane  = tid & 63;
    const int wid   = tid >> 6;
    const int wbase = wid * WSLOTS;
    const int lsw   = lane ^ ((lane >> 3) & 3);  // staging/store lane swizzle
    const int rsw   = (lane >> 1) & 3;           // chunk-read quarter swizzle

    const long rowbase = (long)brow * T * 2;
    const float4* urow4 = (const float4*)(u + rowbase);
    float4*       orow4 = (float4*)(out + rowbase);

    // ---- issue tile-0 staging immediately (hide latency under preamble) ----
    #pragma unroll
    for (int j = 0; j < C / 2; ++j)
        GLOAD_LDS16(urow4 + wbase + j * 64 + lsw, &buf[wbase + j * 64]);

    // ---- preamble (overlaps in-flight loads); uniform mats -> SGPR ----
    const float k  = fabsf(k_w[0]);
    const float bd = fabsf(b_w[0]);
    const float W00 = rfl(im[0] * imask[0] * DT), W01 = rfl(im[1] * imask[1] * DT);
    const float W10 = rfl(im[2] * imask[2] * DT), W11 = rfl(im[3] * imask[3] * DT);

    // x_new = x + v*DT ; v_new = -k*DT*x + (1-b*DT)*v   (row-vec right-mul)
    M2 A = { 1.0f, -k * DT, DT, 1.0f - bd * DT };

    // P[s] = A^(C * 2^s); P[0] = A^8 via 3 squarings; P[6] = A^512 (wave span)
    M2 P[7];
    {
        M2 t = A;
        #pragma unroll
        for (int i = 0; i < 3; ++i) t = mmul(t, t);
        P[0] = t;
        #pragma unroll
        for (int s = 1; s < 7; ++s) P[s] = mmul(P[s - 1], P[s - 1]);
    }
    A = rflm(A);
    #pragma unroll
    for (int s = 0; s < 7; ++s) P[s] = rflm(P[s]);

    // Mlane = A^(C*lane) from bits of lane (per-lane -> VGPR)
    M2 Mlane = { 1.f, 0.f, 0.f, 1.f };
    #pragma unroll
    for (int s = 0; s < 6; ++s)
        if ((lane >> s) & 1) Mlane = mmul(Mlane, P[s]);

    float2 X_init = make_float2(x0[brow * 2 + 0], x0[brow * 2 + 1]);

    constexpr int STEPS = C * BLOCK;   // 2048
    for (int t0 = 0; t0 < T; t0 += STEPS) {
        const int tilebase = t0 / 2;   // float4 slot index of tile start

        // ---- per-wave wait for own staging ----
        asm volatile("s_waitcnt vmcnt(0)" ::: "memory");
        __builtin_amdgcn_sched_barrier(0);

        // ---- read own 64B chunk (swizzled ds_read_b128) + W transform ----
        float2 c[C];
        #pragma unroll
        for (int m = 0; m < C / 2; ++m) {
            float4 t = buf[wbase + lane * (C / 2) + (m ^ rsw)];
            c[2 * m + 0] = make_float2(t.x * W00 + t.y * W10,
                                       t.x * W01 + t.y * W11);
            c[2 * m + 1] = make_float2(t.z * W00 + t.w * W10,
                                       t.z * W01 + t.w * W11);
        }

        // ---- local zero-seeded contribution over C steps ----
        float2 v = make_float2(0.f, 0.f);
        #pragma unroll
        for (int i = 0; i < C; ++i) {
            v = vmul(v, A);
            v.x += c[i].x; v.y += c[i].y;
        }

        // ---- wave-level inclusive scan (64 lanes, 6 steps) ----
        #pragma unroll
        for (int s = 0; s < 6; ++s) {
            float px = __shfl_up(v.x, 1u << s, 64);
            float py = __shfl_up(v.y, 1u << s, 64);
            if (lane >= (1 << s)) {
                float2 pv = vmul(make_float2(px, py), P[s]);
                v.x = pv.x + v.x; v.y = pv.y + v.y;
            }
        }

        // ---- wave total -> slot 0 of OWN region (same-wave ordered) ----
        if (lane == 63) *(float2*)&buf[wbase] = v;
        __syncthreads();                         // barrier 1: tots visible

        // off = state at the start of this wave's 512-step span
        float2 off = X_init;
        for (int w2 = 0; w2 < wid; ++w2) {
            off = vmul(off, P[6]);
            float2 tw = *(const float2*)&buf[w2 * WSLOTS];
            off.x += tw.x; off.y += tw.y;
        }

        // carry to next tile (stashed in regs before tots get clobbered)
        const bool carry = (t0 + STEPS < T);
        float2 fin;
        if (carry) {
            fin = X_init;
            #pragma unroll
            for (int w2 = 0; w2 < NW; ++w2) {
                fin = vmul(fin, P[6]);
                float2 tw = *(const float2*)&buf[w2 * WSLOTS];
                fin.x += tw.x; fin.y += tw.y;
            }
        }

        // exclusive within-wave prefix
        float ex = __shfl_up(v.x, 1u, 64);
        float ey = __shfl_up(v.y, 1u, 64);
        float2 vex = (lane == 0) ? make_float2(0.f, 0.f) : make_float2(ex, ey);

        // start state for this thread's chunk
        float2 X = vmul(off, Mlane);
        X.x += vex.x; X.y += vex.y;

        __syncthreads();                         // barrier 2: tots all read

        // ---- replay C steps in order; write pairs to own swizzled slots ----
        #pragma unroll
        for (int m = 0; m < C / 2; ++m) {
            float4 o;
            X = vmul(X, A);
            X.x += c[2 * m + 0].x; X.y += c[2 * m + 0].y;
            o.x = X.x; o.y = X.y;
            X = vmul(X, A);
            X.x += c[2 * m + 1].x; X.y += c[2 * m + 1].y;
            o.z = X.x; o.w = X.y;
            buf[wbase + lane * (C / 2) + (m ^ rsw)] = o;
        }

        // ---- coalesced store from OWN wave region (wave-ordered LDS) ----
        #pragma unroll
        for (int j = 0; j < C / 2; ++j)
            orow4[tilebase + wbase + j * 64 + lsw] = buf[wbase + j * 64 + lane];

        // ---- restage own region for next tile (wave-local, no barrier) ----
        if (carry) {
            X_init = fin;
            asm volatile("s_waitcnt lgkmcnt(0)" ::: "memory");  // ds reads done
            __builtin_amdgcn_sched_barrier(0);
            const int nb = tilebase + SLOTS;
            #pragma unroll
            for (int j = 0; j < C / 2; ++j)
                GLOAD_LDS16(urow4 + nb + wbase + j * 64 + lsw, &buf[wbase + j * 64]);
        }
    }
}

extern "C" void kernel_launch(void* const* d_in, const int* in_sizes, int n_in,
                              void* d_out, int out_size, void* d_ws, size_t ws_size,
                              hipStream_t stream) {
    const float* u     = (const float*)d_in[0];
    const float* x0    = (const float*)d_in[1];
    const float* k_w   = (const float*)d_in[2];
    const float* b_w   = (const float*)d_in[3];
    const float* im    = (const float*)d_in[4];
    const float* imask = (const float*)d_in[5];
    float* out = (float*)d_out;

    const int B = in_sizes[1] / 2;        // x0 is (B,2)
    const int T = in_sizes[0] / (2 * B);  // u is (B,T,2)

    spring_scan<8, 256><<<B, 256, 0, stream>>>(u, x0, k_w, b_w, im, imask, out, T);
}

// Round 5
// 46.179 us; speedup vs baseline: 1.0310x; 1.0168x over previous
//
#include <hip/hip_runtime.h>
#include <stdint.h>

#define DT (1.0f / 120.0f)

struct M2 { float a00, a01, a10, a11; };

__device__ __forceinline__ M2 mmul(const M2& x, const M2& y) {
    // row-vector convention: v@(X*Y) = (v@X)@Y
    M2 r;
    r.a00 = x.a00 * y.a00 + x.a01 * y.a10;
    r.a01 = x.a00 * y.a01 + x.a01 * y.a11;
    r.a10 = x.a10 * y.a00 + x.a11 * y.a10;
    r.a11 = x.a10 * y.a01 + x.a11 * y.a11;
    return r;
}

__device__ __forceinline__ float2 vmul(float2 v, const M2& m) {
    return make_float2(v.x * m.a00 + v.y * m.a10,
                       v.x * m.a01 + v.y * m.a11);
}

// wave-uniform float -> SGPR
__device__ __forceinline__ float rfl(float x) {
    return __uint_as_float((unsigned)__builtin_amdgcn_readfirstlane((int)__float_as_uint(x)));
}
__device__ __forceinline__ M2 rflm(M2 m) {
    return { rfl(m.a00), rfl(m.a01), rfl(m.a10), rfl(m.a11) };
}

// Async global->LDS, 16B per lane. LDS dest = wave-uniform base + lane*16.
#define GLOAD_LDS16(gp, lp) __builtin_amdgcn_global_load_lds(                 \
    (const __attribute__((address_space(1))) void*)(gp),                      \
    (__attribute__((address_space(3))) void*)(lp), 16, 0, 0)

#define WAITCNT_VM(N)  { asm volatile("s_waitcnt vmcnt(" #N ")" ::: "memory"); \
                         __builtin_amdgcn_sched_barrier(0); }
#define BARRIER_LGKM() { asm volatile("s_waitcnt lgkmcnt(0)" ::: "memory");    \
                         __builtin_amdgcn_sched_barrier(0);                    \
                         __builtin_amdgcn_s_barrier();                         \
                         __builtin_amdgcn_sched_barrier(0); }

// ============================================================================
// Pipelined 2-tile kernel (T == 2 * C * BLOCK exactly).
// Linear-recurrence parallel scan: X_t = X_{t-1} @ A + u_t @ W.
// All global traffic coalesced via per-wave LDS bounce, slot swizzle
//   f(s): low 2 bits of slot s XOR'd with ((lane-group)>>1)&3  (involution).
// Schedule: stage BOTH tiles up front; per tile wait vmcnt(4) (counted —
// never drains the pipe: tile-1 loads stay in flight across tile-0's
// barrier and stores); one raw s_barrier + lgkmcnt(0) per tile for the
// 4-entry wave-total exchange (tot[] double-buffered per tile).
// ============================================================================
template <int C, int BLOCK>
__global__ __launch_bounds__(BLOCK) void spring_scan_pipe(
    const float* __restrict__ u, const float* __restrict__ x0,
    const float* __restrict__ k_w, const float* __restrict__ b_w,
    const float* __restrict__ im, const float* __restrict__ imask,
    float* __restrict__ out)
{
    static_assert(C == 8, "squaring count + swizzle assume C==8");
    constexpr int NW     = BLOCK / 64;     // 4 waves
    constexpr int SLOTS  = BLOCK * C / 2;  // 1024 float4 slots / tile (16 KiB)
    constexpr int WSLOTS = 64 * C / 2;     // 256 slots per wave region

    __shared__ float4 buf[2][SLOTS];       // 32 KiB double buffer
    __shared__ float2 tot[2][NW];          // per-tile wave totals

    const int brow  = blockIdx.x;
    const int tid   = threadIdx.x;
    const int lane  = tid & 63;
    const int wid   = tid >> 6;
    const int wbase = wid * WSLOTS;
    const int lsw   = lane ^ ((lane >> 3) & 3);  // staging/store lane swizzle
    const int rsw   = (lane >> 1) & 3;           // chunk-read quarter swizzle

    constexpr int T = 2 * C * BLOCK;
    const long rowbase = (long)brow * T * 2;
    const float4* urow4 = (const float4*)(u + rowbase);
    float4*       orow4 = (float4*)(out + rowbase);

    // ---- stage BOTH tiles immediately (8 loads in flight per wave) ----
    #pragma unroll
    for (int tb = 0; tb < 2; ++tb)
        #pragma unroll
        for (int j = 0; j < C / 2; ++j)
            GLOAD_LDS16(urow4 + tb * SLOTS + wbase + j * 64 + lsw,
                        &buf[tb][wbase + j * 64]);

    // ---- preamble (overlaps in-flight loads); uniform mats -> SGPR ----
    const float k  = fabsf(k_w[0]);
    const float bd = fabsf(b_w[0]);
    const float W00 = rfl(im[0] * imask[0] * DT), W01 = rfl(im[1] * imask[1] * DT);
    const float W10 = rfl(im[2] * imask[2] * DT), W11 = rfl(im[3] * imask[3] * DT);

    // x_new = x + v*DT ; v_new = -k*DT*x + (1-b*DT)*v   (row-vec right-mul)
    M2 A = { 1.0f, -k * DT, DT, 1.0f - bd * DT };

    // P[s] = A^(C * 2^s); P[0] = A^8 via 3 squarings; P[6] = A^512 (wave span)
    M2 P[7];
    {
        M2 t = A;
        #pragma unroll
        for (int i = 0; i < 3; ++i) t = mmul(t, t);
        P[0] = t;
        #pragma unroll
        for (int s = 1; s < 7; ++s) P[s] = mmul(P[s - 1], P[s - 1]);
    }
    A = rflm(A);
    #pragma unroll
    for (int s = 0; s < 7; ++s) P[s] = rflm(P[s]);

    // Mlane = A^(C*lane) from bits of lane (per-lane -> VGPR)
    M2 Mlane = { 1.f, 0.f, 0.f, 1.f };
    #pragma unroll
    for (int s = 0; s < 6; ++s)
        if ((lane >> s) & 1) Mlane = mmul(Mlane, P[s]);

    float2 X_init = make_float2(x0[brow * 2 + 0], x0[brow * 2 + 1]);

    #pragma unroll
    for (int tb = 0; tb < 2; ++tb) {
        // Counted wait — never 0.  Per-wave queue:
        //   tb=0: [L0 x4][L1 x4]      -> vmcnt(4) guarantees L0 done
        //   tb=1: [L1 x4][S0 x4]      -> vmcnt(4) guarantees L1 done
        WAITCNT_VM(4);

        // ---- read own 64B chunk (swizzled ds_read_b128) + W transform ----
        float2 c[C];
        #pragma unroll
        for (int m = 0; m < C / 2; ++m) {
            float4 t = buf[tb][wbase + lane * (C / 2) + (m ^ rsw)];
            c[2 * m + 0] = make_float2(t.x * W00 + t.y * W10,
                                       t.x * W01 + t.y * W11);
            c[2 * m + 1] = make_float2(t.z * W00 + t.w * W10,
                                       t.z * W01 + t.w * W11);
        }

        // ---- local zero-seeded contribution over C steps ----
        float2 v = make_float2(0.f, 0.f);
        #pragma unroll
        for (int i = 0; i < C; ++i) {
            v = vmul(v, A);
            v.x += c[i].x; v.y += c[i].y;
        }

        // ---- wave-level inclusive scan (64 lanes, 6 steps) ----
        #pragma unroll
        for (int s = 0; s < 6; ++s) {
            float px = __shfl_up(v.x, 1u << s, 64);
            float py = __shfl_up(v.y, 1u << s, 64);
            if (lane >= (1 << s)) {
                float2 pv = vmul(make_float2(px, py), P[s]);
                v.x = pv.x + v.x; v.y = pv.y + v.y;
            }
        }

        // ---- wave total exchange: ONE barrier, lgkm-only (loads in flight) ----
        if (lane == 63) tot[tb][wid] = v;
        BARRIER_LGKM();

        // off = state at the start of this wave's 512-step span
        float2 off = X_init;
        for (int w2 = 0; w2 < wid; ++w2) {
            off = vmul(off, P[6]);
            float2 tw = tot[tb][w2];
            off.x += tw.x; off.y += tw.y;
        }

        // carry for tile 1 (computed once, from tile-0 totals)
        if (tb == 0) {
            float2 fin = X_init;
            #pragma unroll
            for (int w2 = 0; w2 < NW; ++w2) {
                fin = vmul(fin, P[6]);
                float2 tw = tot[0][w2];
                fin.x += tw.x; fin.y += tw.y;
            }
            // used after this tile; totals are tb-indexed so no clobber race
            if (lane == 0) {}  // keep structure simple; fin assigned below
            X_init = (wid >= 0) ? X_init : X_init;  // no-op, clarity only
            // stash carry now:
            // (applied at loop bottom)
            // store in a register:
            // -- see below
            // (we fold it directly:)
            // X_init update deferred to after replay? No: X only needs 'off'.
            // Safe to update now; 'off' already captured.
            X_init = fin;
        }

        // exclusive within-wave prefix
        float ex = __shfl_up(v.x, 1u, 64);
        float ey = __shfl_up(v.y, 1u, 64);
        float2 vex = (lane == 0) ? make_float2(0.f, 0.f) : make_float2(ex, ey);

        // start state for this thread's chunk
        float2 X = vmul(off, Mlane);
        X.x += vex.x; X.y += vex.y;

        // ---- replay C steps in order; write pairs to own swizzled slots ----
        #pragma unroll
        for (int m = 0; m < C / 2; ++m) {
            float4 o;
            X = vmul(X, A);
            X.x += c[2 * m + 0].x; X.y += c[2 * m + 0].y;
            o.x = X.x; o.y = X.y;
            X = vmul(X, A);
            X.x += c[2 * m + 1].x; X.y += c[2 * m + 1].y;
            o.z = X.x; o.w = X.y;
            buf[tb][wbase + lane * (C / 2) + (m ^ rsw)] = o;
        }

        // ---- coalesced store from OWN wave region (wave-ordered LDS) ----
        #pragma unroll
        for (int j = 0; j < C / 2; ++j)
            orow4[tb * SLOTS + wbase + j * 64 + lsw] = buf[tb][wbase + j * 64 + lane];
    }
}

// ============================================================================
// Generic fallback (any T multiple of C*BLOCK) — R3 structure.
// ============================================================================
template <int C, int BLOCK>
__global__ __launch_bounds__(BLOCK) void spring_scan_gen(
    const float* __restrict__ u, const float* __restrict__ x0,
    const float* __restrict__ k_w, const float* __restrict__ b_w,
    const float* __restrict__ im, const float* __restrict__ imask,
    float* __restrict__ out, int T)
{
    static_assert(C == 8, "swizzle assumes C==8");
    constexpr int NW     = BLOCK / 64;
    constexpr int SLOTS  = BLOCK * C / 2;
    constexpr int WSLOTS = 64 * C / 2;

    __shared__ float4 buf[SLOTS];
    __shared__ float2 tots[NW];

    const int brow  = blockIdx.x;
    const int tid   = threadIdx.x;
    const int lane  = tid & 63;
    const int wid   = tid >> 6;
    const int wbase = wid * WSLOTS;
    const int lsw   = lane ^ ((lane >> 3) & 3);
    const int rsw   = (lane >> 1) & 3;

    const long rowbase = (long)brow * T * 2;
    const float4* urow4 = (const float4*)(u + rowbase);
    float4*       orow4 = (float4*)(out + rowbase);

    #pragma unroll
    for (int j = 0; j < C / 2; ++j)
        GLOAD_LDS16(urow4 + wbase + j * 64 + lsw, &buf[wbase + j * 64]);

    const float k  = fabsf(k_w[0]);
    const float bd = fabsf(b_w[0]);
    const float W00 = rfl(im[0] * imask[0] * DT), W01 = rfl(im[1] * imask[1] * DT);
    const float W10 = rfl(im[2] * imask[2] * DT), W11 = rfl(im[3] * imask[3] * DT);

    M2 A = { 1.0f, -k * DT, DT, 1.0f - bd * DT };
    M2 P[7];
    {
        M2 t = A;
        #pragma unroll
        for (int i = 0; i < 3; ++i) t = mmul(t, t);
        P[0] = t;
        #pragma unroll
        for (int s = 1; s < 7; ++s) P[s] = mmul(P[s - 1], P[s - 1]);
    }
    A = rflm(A);
    #pragma unroll
    for (int s = 0; s < 7; ++s) P[s] = rflm(P[s]);

    M2 Mlane = { 1.f, 0.f, 0.f, 1.f };
    #pragma unroll
    for (int s = 0; s < 6; ++s)
        if ((lane >> s) & 1) Mlane = mmul(Mlane, P[s]);

    float2 X_init = make_float2(x0[brow * 2 + 0], x0[brow * 2 + 1]);

    constexpr int STEPS = C * BLOCK;
    for (int t0 = 0; t0 < T; t0 += STEPS) {
        const int tilebase = t0 / 2;

        asm volatile("s_waitcnt vmcnt(0)" ::: "memory");
        __builtin_amdgcn_sched_barrier(0);

        float2 c[C];
        #pragma unroll
        for (int m = 0; m < C / 2; ++m) {
            float4 t = buf[wbase + lane * (C / 2) + (m ^ rsw)];
            c[2 * m + 0] = make_float2(t.x * W00 + t.y * W10,
                                       t.x * W01 + t.y * W11);
            c[2 * m + 1] = make_float2(t.z * W00 + t.w * W10,
                                       t.z * W01 + t.w * W11);
        }

        float2 v = make_float2(0.f, 0.f);
        #pragma unroll
        for (int i = 0; i < C; ++i) {
            v = vmul(v, A);
            v.x += c[i].x; v.y += c[i].y;
        }

        #pragma unroll
        for (int s = 0; s < 6; ++s) {
            float px = __shfl_up(v.x, 1u << s, 64);
            float py = __shfl_up(v.y, 1u << s, 64);
            if (lane >= (1 << s)) {
                float2 pv = vmul(make_float2(px, py), P[s]);
                v.x = pv.x + v.x; v.y = pv.y + v.y;
            }
        }

        if (lane == 63) tots[wid] = v;
        __syncthreads();

        float2 off = X_init;
        for (int w2 = 0; w2 < wid; ++w2) {
            off = vmul(off, P[6]);
            off.x += tots[w2].x; off.y += tots[w2].y;
        }

        const bool carry = (t0 + STEPS < T);
        float2 fin;
        if (carry) {
            fin = X_init;
            #pragma unroll
            for (int w2 = 0; w2 < NW; ++w2) {
                fin = vmul(fin, P[6]);
                fin.x += tots[w2].x; fin.y += tots[w2].y;
            }
        }

        float ex = __shfl_up(v.x, 1u, 64);
        float ey = __shfl_up(v.y, 1u, 64);
        float2 vex = (lane == 0) ? make_float2(0.f, 0.f) : make_float2(ex, ey);

        float2 X = vmul(off, Mlane);
        X.x += vex.x; X.y += vex.y;

        __syncthreads();

        #pragma unroll
        for (int m = 0; m < C / 2; ++m) {
            float4 o;
            X = vmul(X, A);
            X.x += c[2 * m + 0].x; X.y += c[2 * m + 0].y;
            o.x = X.x; o.y = X.y;
            X = vmul(X, A);
            X.x += c[2 * m + 1].x; X.y += c[2 * m + 1].y;
            o.z = X.x; o.w = X.y;
            buf[wbase + lane * (C / 2) + (m ^ rsw)] = o;
        }

        #pragma unroll
        for (int j = 0; j < C / 2; ++j)
            orow4[tilebase + wbase + j * 64 + lsw] = buf[wbase + j * 64 + lane];

        if (carry) {
            X_init = fin;
            asm volatile("s_waitcnt lgkmcnt(0)" ::: "memory");
            __builtin_amdgcn_sched_barrier(0);
            const int nb = tilebase + SLOTS;
            #pragma unroll
            for (int j = 0; j < C / 2; ++j)
                GLOAD_LDS16(urow4 + nb + wbase + j * 64 + lsw, &buf[wbase + j * 64]);
        }
    }
}

extern "C" void kernel_launch(void* const* d_in, const int* in_sizes, int n_in,
                              void* d_out, int out_size, void* d_ws, size_t ws_size,
                              hipStream_t stream) {
    const float* u     = (const float*)d_in[0];
    const float* x0    = (const float*)d_in[1];
    const float* k_w   = (const float*)d_in[2];
    const float* b_w   = (const float*)d_in[3];
    const float* im    = (const float*)d_in[4];
    const float* imask = (const float*)d_in[5];
    float* out = (float*)d_out;

    const int B = in_sizes[1] / 2;        // x0 is (B,2)
    const int T = in_sizes[0] / (2 * B);  // u is (B,T,2)

    constexpr int C = 8, BLOCK = 256;
    if (T == 2 * C * BLOCK) {
        spring_scan_pipe<C, BLOCK><<<B, BLOCK, 0, stream>>>(
            u, x0, k_w, b_w, im, imask, out);
    } else {
        spring_scan_gen<C, BLOCK><<<B, BLOCK, 0, stream>>>(
            u, x0, k_w, b_w, im, imask, out, T);
    }
}